// Round 14
// baseline (1105.174 us; speedup 1.0000x reference)
//
#include <hip/hip_runtime.h>
#include <cstdint>

typedef _Float16 half2_t __attribute__((ext_vector_type(2)));
typedef _Float16 half8_t __attribute__((ext_vector_type(8)));
typedef float    floatx4 __attribute__((ext_vector_type(4)));

// ---------------- workspace layout (bytes) ----------------
#define OFF_BIAS  0ull
#define SZ_BIAS   (1536ull*4)                  // b_ih + b_hh(r,z) folded, f32
#define OFF_GI    6144ull                      // gi f16 [2][32768][768] (~100.7 MB)

// ---------------- prep: bias fold only (verified) ----------------
__global__ void k_prep(const float* __restrict__ bih1, const float* __restrict__ bih2,
                       const float* __restrict__ bhh1, const float* __restrict__ bhh2,
                       float* __restrict__ biascat) {
    int q3 = blockIdx.x * 256 + threadIdx.x;
    if (q3 < 1536) {
        // fold b_ih (all gates) + b_hh (r,z only; n-gate's b_hh is inside r*(...))
        int dir = q3 >= 768;  int j = q3 - dir*768;
        const float* bi = dir ? bih2 : bih1;
        const float* bh = dir ? bhh2 : bhh1;
        biascat[q3] = bi[j] + (j < 512 ? bh[j] : 0.f);
    }
}

// ---------------- shared helper (verified in k_gemm since round 3) ----------------
__device__ __forceinline__ half8_t cvt8(float4 a, float4 b) {
    half8_t r;
    r[0] = (_Float16)a.x; r[1] = (_Float16)a.y; r[2] = (_Float16)a.z; r[3] = (_Float16)a.w;
    r[4] = (_Float16)b.x; r[5] = (_Float16)b.y; r[6] = (_Float16)b.z; r[7] = (_Float16)b.w;
    return r;
}

// ---------------- gi GEMM (verified, source-identical) ----------------
__global__ __launch_bounds__(256) void k_gemm(const float* __restrict__ x,
                                              const float* __restrict__ Wih1,
                                              const float* __restrict__ Wih2,
                                              const float* __restrict__ bias,
                                              _Float16* __restrict__ gi) {
    __shared__ __align__(16) _Float16 As[128*32];   // [m][k], LD=32
    __shared__ __align__(16) _Float16 Bs[256*32];   // [n][k], LD=32
    const int tid = threadIdx.x;
    const int m0 = blockIdx.x * 128;
    const int n0 = blockIdx.y * 256;                // 768 = 3*256: no dir straddle
    const int lane = tid & 63, wave = tid >> 6;
    const int wr = wave >> 1, wc = wave & 1;        // 2x2 waves: 64M x 128N each
    floatx4 acc[4][8];
#pragma unroll
    for (int i = 0; i < 4; ++i)
#pragma unroll
        for (int j = 0; j < 8; ++j) acc[i][j] = (floatx4)0.f;

    const float* Wsrc = (n0 < 768) ? Wih1 : Wih2;
    const int nl = (n0 < 768) ? n0 : (n0 - 768);
    const int ar = tid >> 1, ah = (tid & 1) * 16;   // A: 2 threads/row, 16 cols each
    const float* Ag = x + (size_t)(m0 + ar)*512 + ah;
    const float* Bg = Wsrc + (size_t)(nl + tid)*512; // B: 1 thread/row, 32 cols
    _Float16* Aw = As + ar*32 + ah;
    _Float16* Bw = Bs + tid*32;
    const int aoff = (wr*64  + (lane & 15))*32 + (lane >> 4)*8;
    const int boff = (wc*128 + (lane & 15))*32 + (lane >> 4)*8;

    for (int kt = 0; kt < 16; ++kt) {
        const int ko = kt*32;
        float4 a0 = *(const float4*)(Ag + ko);
        float4 a1 = *(const float4*)(Ag + ko + 4);
        float4 a2 = *(const float4*)(Ag + ko + 8);
        float4 a3 = *(const float4*)(Ag + ko + 12);
        float4 b0 = *(const float4*)(Bg + ko);
        float4 b1 = *(const float4*)(Bg + ko + 4);
        float4 b2 = *(const float4*)(Bg + ko + 8);
        float4 b3 = *(const float4*)(Bg + ko + 12);
        float4 b4 = *(const float4*)(Bg + ko + 16);
        float4 b5 = *(const float4*)(Bg + ko + 20);
        float4 b6 = *(const float4*)(Bg + ko + 24);
        float4 b7 = *(const float4*)(Bg + ko + 28);
        __syncthreads();                       // prev tile's LDS reads complete
        *(half8_t*)(Aw)      = cvt8(a0, a1);
        *(half8_t*)(Aw + 8)  = cvt8(a2, a3);
        *(half8_t*)(Bw)      = cvt8(b0, b1);
        *(half8_t*)(Bw + 8)  = cvt8(b2, b3);
        *(half8_t*)(Bw + 16) = cvt8(b4, b5);
        *(half8_t*)(Bw + 24) = cvt8(b6, b7);
        __syncthreads();
        half8_t af[4], bf[8];
#pragma unroll
        for (int f = 0; f < 4; ++f) af[f] = *(const half8_t*)(As + aoff + f*512);
#pragma unroll
        for (int f = 0; f < 8; ++f) bf[f] = *(const half8_t*)(Bs + boff + f*512);
#pragma unroll
        for (int i = 0; i < 4; ++i)
#pragma unroll
            for (int j = 0; j < 8; ++j)
                acc[i][j] = __builtin_amdgcn_mfma_f32_16x16x32_f16(af[i], bf[j], acc[i][j], 0, 0, 0);
    }
    // epilogue: +bias, f16, split into gi[dir][row][col]
#pragma unroll
    for (int i = 0; i < 4; ++i) {
#pragma unroll
        for (int j = 0; j < 8; ++j) {
            int col = n0 + wc*128 + j*16 + (lane & 15);
            float bv = bias[col];
            int dir = col >= 768;
            size_t gib = (size_t)dir * 25165824ull + (size_t)(col - dir*768);
#pragma unroll
            for (int q = 0; q < 4; ++q) {
                int row = m0 + wr*64 + i*16 + (lane >> 4)*4 + q;
                gi[gib + (size_t)row*768] = (_Float16)(acc[i][j][q] + bv);
            }
        }
    }
}

// ---------------- recurrent kernel: 1 WG per (direction, batch) sequence ----------------
// R14: W register file split VGPR(72) + AGPR(120 via inline-asm "a" pins).
// The backend's arch-VGPR budget (2 WGs/CU: T=512 -> 128, immune to all
// attributes, R7..R13) forced full-W scratch restream (384KB/WG/step = 3024cy
// = the measured 646us). AGPRs are a separate allocation channel on the gfx950
// unified file: 2 waves/SIMD -> 256 combined regs/thread available.
// Also: mask in {0,1} is WG-uniform -> mask==0 steps skip entirely (~10%).
#define FDOT2(w_, h_, acc_) __builtin_amdgcn_fdot2(__builtin_bit_cast(half2_t,(w_)), (h_), (acc_), false)
#define LBAR()  do { asm volatile("s_waitcnt lgkmcnt(0)" ::: "memory"); \
                     __builtin_amdgcn_s_barrier(); } while (0)

// pack W[c + a*256][kh*128 + 2q .. +1] into one f16x2 u32
#define PACKW(a_, q_) __extension__({ \
    float2 f_ = *(const float2*)(W + (size_t)(c + (a_)*256)*256 + kh*128 + 2*(q_)); \
    half2_t hp_ = {(_Float16)f_.x, (_Float16)f_.y}; \
    __builtin_bit_cast(unsigned int, hp_); })

#define A_DEF(K) unsigned aR##K##_0, aR##K##_1, aR##K##_2, aR##K##_3, \
                          aZ##K##_0, aZ##K##_1, aZ##K##_2, aZ##K##_3, \
                          aN##K##_0, aN##K##_1, aN##K##_2, aN##K##_3
#define AWR(v_, a_, q_) asm volatile("v_accvgpr_write_b32 %0, %1" : "=a"(v_) : "v"(PACKW(a_, q_)))
#define A_INIT(K) do { \
    AWR(aR##K##_0, 0, (K)*4+0); AWR(aR##K##_1, 0, (K)*4+1); \
    AWR(aR##K##_2, 0, (K)*4+2); AWR(aR##K##_3, 0, (K)*4+3); \
    AWR(aZ##K##_0, 1, (K)*4+0); AWR(aZ##K##_1, 1, (K)*4+1); \
    AWR(aZ##K##_2, 1, (K)*4+2); AWR(aZ##K##_3, 1, (K)*4+3); \
    AWR(aN##K##_0, 2, (K)*4+0); AWR(aN##K##_1, 2, (K)*4+1); \
    AWR(aN##K##_2, 2, (K)*4+2); AWR(aN##K##_3, 2, (K)*4+3); } while (0)
#define ARD(d_, s_) asm volatile("v_accvgpr_read_b32 %0, %1" : "=v"(d_) : "a"(s_))

#define A_DOTK(K) do { \
    half8_t hv_ = *(const half8_t*)(hrd + ((K) << 3)); \
    half2_t h0_ = {hv_[0], hv_[1]}, h1_ = {hv_[2], hv_[3]}; \
    half2_t h2_ = {hv_[4], hv_[5]}, h3_ = {hv_[6], hv_[7]}; \
    unsigned r0_, r1_, r2_, r3_, z0_, z1_, z2_, z3_, n0_, n1_, n2_, n3_; \
    ARD(r0_, aR##K##_0); ARD(r1_, aR##K##_1); ARD(r2_, aR##K##_2); ARD(r3_, aR##K##_3); \
    a0 = FDOT2(r0_, h0_, a0);  b0 = FDOT2(r1_, h1_, b0); \
    a0 = FDOT2(r2_, h2_, a0);  b0 = FDOT2(r3_, h3_, b0); \
    ARD(z0_, aZ##K##_0); ARD(z1_, aZ##K##_1); ARD(z2_, aZ##K##_2); ARD(z3_, aZ##K##_3); \
    a1 = FDOT2(z0_, h0_, a1);  b1 = FDOT2(z1_, h1_, b1); \
    a1 = FDOT2(z2_, h2_, a1);  b1 = FDOT2(z3_, h3_, b1); \
    ARD(n0_, aN##K##_0); ARD(n1_, aN##K##_1); ARD(n2_, aN##K##_2); ARD(n3_, aN##K##_3); \
    a2 = FDOT2(n0_, h0_, a2);  b2 = FDOT2(n1_, h1_, b2); \
    a2 = FDOT2(n2_, h2_, a2);  b2 = FDOT2(n3_, h3_, b2); } while (0)

__global__ __launch_bounds__(512) void k_rnn(const float* __restrict__ Whh1,
                                             const float* __restrict__ Whh2,
                                             const _Float16* __restrict__ gi,
                                             const float* __restrict__ mask,
                                             const float* __restrict__ bhh1,
                                             const float* __restrict__ bhh2,
                                             float* __restrict__ outp) {
    __shared__ __align__(16) _Float16 hs16[256];     // h as f16
    __shared__ float part[768];                      // kh=1 partial sums
    const int tid = threadIdx.x;
    const int bid = blockIdx.x;                      // 0..127
    const int dir = bid >> 6, b = bid & 63;
    const int c  = tid & 255;                        // column this thread owns
    const int kh = tid >> 8;                         // K half

    const float* W = dir ? Whh2 : Whh1;              // (768, 256) row-major

    // VGPR part: kk 0..5 -> w[a*24 + kk*4 + t], cols kh*128 + 2*(kk*4+t)
    unsigned int w[72];
#pragma unroll
    for (int a = 0; a < 3; ++a)
#pragma unroll
        for (int qq = 0; qq < 24; ++qq)
            w[a*24 + qq] = PACKW(a, qq);

    // AGPR part: kk 6..15 -> 120 named AGPRs
    A_DEF(6);  A_DEF(7);  A_DEF(8);  A_DEF(9);  A_DEF(10);
    A_DEF(11); A_DEF(12); A_DEF(13); A_DEF(14); A_DEF(15);
    A_INIT(6);  A_INIT(7);  A_INIT(8);  A_INIT(9);  A_INIT(10);
    A_INIT(11); A_INIT(12); A_INIT(13); A_INIT(14); A_INIT(15);

    const float bhn = (dir ? bhh2 : bhh1)[512 + c];

    if (tid < 256) hs16[tid] = (_Float16)0.f;
    float h_c = 0.f;
    __syncthreads();

    const _Float16* gb = gi + (size_t)dir * 25165824ull + c;
    const _Float16* hrd = hs16 + (kh << 7);          // this thread's K-half base

#pragma unroll 1
    for (int s = 0; s < 512; ++s) {
        const int t = dir ? (511 - s) : s;
        const float mv = mask[t*64 + b];             // WG-uniform: b fixed per WG
        if (mv != 0.f) {                             // mask==1 step
            float g0 = 0.f, g1 = 0.f, g2 = 0.f;
            if (tid < 256) {
                const _Float16* gp = gb + (size_t)(t*64 + b)*768;
                g0 = (float)gp[0];                   // i_r (+b_ih_r+b_hh_r folded)
                g1 = (float)gp[256];                 // i_z (+b_ih_z+b_hh_z folded)
                g2 = (float)gp[512];                 // i_n (+b_ih_n folded)
            }
            float a0 = 0.f, a1 = 0.f, a2 = 0.f;
            float b0 = 0.f, b1 = 0.f, b2 = 0.f;      // second chains for ILP
#pragma unroll
            for (int kk = 0; kk < 6; ++kk) {         // VGPR-resident kk
                half8_t hv = *(const half8_t*)(hrd + (kk << 3));
                half2_t h0 = {hv[0], hv[1]};
                half2_t h1 = {hv[2], hv[3]};
                half2_t h2 = {hv[4], hv[5]};
                half2_t h3 = {hv[6], hv[7]};
                const int q = kk << 2;
                a0 = FDOT2(w[     q + 0], h0, a0);  b0 = FDOT2(w[     q + 1], h1, b0);
                a0 = FDOT2(w[     q + 2], h2, a0);  b0 = FDOT2(w[     q + 3], h3, b0);
                a1 = FDOT2(w[24 + q + 0], h0, a1);  b1 = FDOT2(w[24 + q + 1], h1, b1);
                a1 = FDOT2(w[24 + q + 2], h2, a1);  b1 = FDOT2(w[24 + q + 3], h3, b1);
                a2 = FDOT2(w[48 + q + 0], h0, a2);  b2 = FDOT2(w[48 + q + 1], h1, b2);
                a2 = FDOT2(w[48 + q + 2], h2, a2);  b2 = FDOT2(w[48 + q + 3], h3, b2);
            }
            A_DOTK(6);  A_DOTK(7);  A_DOTK(8);  A_DOTK(9);  A_DOTK(10);
            A_DOTK(11); A_DOTK(12); A_DOTK(13); A_DOTK(14); A_DOTK(15);
            a0 += b0; a1 += b1; a2 += b2;
            if (tid >= 256) { part[c] = a0; part[256 + c] = a1; part[512 + c] = a2; }
            LBAR();                                  // part visible; hs16 reads done
            if (tid < 256) {
                float ghr = a0 + part[c];
                float ghz = a1 + part[256 + c];
                float ghn = a2 + part[512 + c];
                float r = 1.f / (1.f + __expf(-(g0 + ghr)));
                float z = 1.f / (1.f + __expf(-(g1 + ghz)));
                float tt = g2 + r * (ghn + bhn);
                float ea = __expf(-2.f * fabsf(tt)); // overflow-safe tanh
                float nt = (1.f - ea) / (1.f + ea);
                nt = (tt < 0.f) ? -nt : nt;
                float ht = (1.f - z) * nt + z * h_c;
                h_c = ht;                            // mv==1: hm = ht
                hs16[c] = (_Float16)ht;              // typed f16 store
                outp[(size_t)(t*64 + b)*512 + dir*256 + c] = ht;
            }
            LBAR();                                  // hs16 visible for next step
        } else {                                     // mask==0 step: h unchanged
            if (tid < 256)
                outp[(size_t)(t*64 + b)*512 + dir*256 + c] = 0.f;
        }
    }
    if (tid < 256) {
        outp[16777216u + dir*16384 + b*256 + c] = h_c;   // hidden[dir][b][c]
    }
}

// ---------------- launch ----------------
extern "C" void kernel_launch(void* const* d_in, const int* in_sizes, int n_in,
                              void* d_out, int out_size, void* d_ws, size_t ws_size,
                              hipStream_t stream) {
    const float* x    = (const float*)d_in[0];
    const float* mask = (const float*)d_in[1];
    const float* Wih1 = (const float*)d_in[2];
    const float* Whh1 = (const float*)d_in[3];
    const float* bih1 = (const float*)d_in[4];
    const float* bhh1 = (const float*)d_in[5];
    const float* Wih2 = (const float*)d_in[6];
    const float* Whh2 = (const float*)d_in[7];
    const float* bih2 = (const float*)d_in[8];
    const float* bhh2 = (const float*)d_in[9];
    char* ws = (char*)d_ws;
    float* biascat = (float*)(ws + OFF_BIAS);
    _Float16* gi   = (_Float16*)(ws + OFF_GI);
    float* outp = (float*)d_out;

    hipLaunchKernelGGL(k_prep, dim3(6), dim3(256), 0, stream,
                       bih1, bih2, bhh1, bhh2, biascat);
    hipLaunchKernelGGL(k_gemm, dim3(256, 6), dim3(256), 0, stream, x, Wih1, Wih2, biascat, gi);
    hipLaunchKernelGGL(k_rnn, dim3(128), dim3(512), 0, stream,
                       Whh1, Whh2, gi, mask, bhh1, bhh2, outp);
}

// Round 16
// 917.297 us; speedup vs baseline: 1.2048x; 1.2048x over previous
//
#include <hip/hip_runtime.h>
#include <cstdint>

typedef _Float16 half2_t __attribute__((ext_vector_type(2)));
typedef _Float16 half8_t __attribute__((ext_vector_type(8)));
typedef float    floatx4 __attribute__((ext_vector_type(4)));

// ---------------- workspace layout (bytes) ----------------
#define OFF_BIAS  0ull
#define SZ_BIAS   (1536ull*4)
#define OFF_WP    8192ull                      // packed W: [dir][48][512] half8 = 768 KB
#define SZ_WP     (2ull*48*512*16)
#define OFF_GI    (OFF_WP + SZ_WP)             // gi f16 [2][32768][768] (~100.7 MB)

// W group table (G=0..47, 4 consecutive pairs p each; pair p = k 2p..2p+1 of the kh-half):
//  G 0..15  gate0 p=4G         -> REG wreg[G]
//  G 16..20 gate1 p=4(G-16)    -> REG wreg[G]    (pq 0..4)
//  G 21..31 gate1 p=20+4(G-21) -> LDS L=G-21 (0..10)   (pq 5..15)
//  G 32..38 gate2 p=4(G-32)    -> LDS L=G-21 (11..17)  (pq 0..6)
//  G 39..47 gate2 p=28+4(G-39) -> STR S=G-39 (0..8)    (pq 7..15)
__device__ __forceinline__ void group_ap(int G, int& a, int& p0) {
    if (G < 16)      { a = 0; p0 = 4*G; }
    else if (G < 21) { a = 1; p0 = 4*(G-16); }
    else if (G < 32) { a = 1; p0 = 20 + 4*(G-21); }
    else if (G < 39) { a = 2; p0 = 4*(G-32); }
    else             { a = 2; p0 = 28 + 4*(G-39); }
}

// ---------------- prep: bias fold + W pack (half8_t containers only) ----------------
__global__ void k_prep(const float* __restrict__ Whh1, const float* __restrict__ Whh2,
                       const float* __restrict__ bih1, const float* __restrict__ bih2,
                       const float* __restrict__ bhh1, const float* __restrict__ bhh2,
                       _Float16* __restrict__ wp, float* __restrict__ biascat) {
    int idx = blockIdx.x * 256 + threadIdx.x;
    if (idx < 2*48*512) {
        int i   = idx & 511;
        int G   = (idx >> 9) % 48;
        int dir = idx / (48*512);
        int c = i & 255, kh = i >> 8;
        int a, p0;  group_ap(G, a, p0);
        const float* W = dir ? Whh2 : Whh1;          // (768,256) row-major
        const float* row = W + (size_t)(c + a*256)*256 + kh*128;
        half8_t v;                                   // cvt8-style element writes (proven)
#pragma unroll
        for (int q = 0; q < 4; ++q) {
            float2 f = *(const float2*)(row + 2*(p0 + q));
            v[2*q]   = (_Float16)f.x;
            v[2*q+1] = (_Float16)f.y;
        }
        *(half8_t*)(wp + 8ull*idx) = v;
    } else {
        int q3 = idx - 2*48*512;
        if (q3 < 1536) {
            int dir = q3 >= 768;  int j = q3 - dir*768;
            const float* bi = dir ? bih2 : bih1;
            const float* bh = dir ? bhh2 : bhh1;
            biascat[q3] = bi[j] + (j < 512 ? bh[j] : 0.f);
        }
    }
}

// ---------------- shared helper (verified) ----------------
__device__ __forceinline__ half8_t cvt8(float4 a, float4 b) {
    half8_t r;
    r[0] = (_Float16)a.x; r[1] = (_Float16)a.y; r[2] = (_Float16)a.z; r[3] = (_Float16)a.w;
    r[4] = (_Float16)b.x; r[5] = (_Float16)b.y; r[6] = (_Float16)b.z; r[7] = (_Float16)b.w;
    return r;
}

// ---------------- gi GEMM (verified, source-identical) ----------------
__global__ __launch_bounds__(256) void k_gemm(const float* __restrict__ x,
                                              const float* __restrict__ Wih1,
                                              const float* __restrict__ Wih2,
                                              const float* __restrict__ bias,
                                              _Float16* __restrict__ gi) {
    __shared__ __align__(16) _Float16 As[128*32];
    __shared__ __align__(16) _Float16 Bs[256*32];
    const int tid = threadIdx.x;
    const int m0 = blockIdx.x * 128;
    const int n0 = blockIdx.y * 256;
    const int lane = tid & 63, wave = tid >> 6;
    const int wr = wave >> 1, wc = wave & 1;
    floatx4 acc[4][8];
#pragma unroll
    for (int i = 0; i < 4; ++i)
#pragma unroll
        for (int j = 0; j < 8; ++j) acc[i][j] = (floatx4)0.f;

    const float* Wsrc = (n0 < 768) ? Wih1 : Wih2;
    const int nl = (n0 < 768) ? n0 : (n0 - 768);
    const int ar = tid >> 1, ah = (tid & 1) * 16;
    const float* Ag = x + (size_t)(m0 + ar)*512 + ah;
    const float* Bg = Wsrc + (size_t)(nl + tid)*512;
    _Float16* Aw = As + ar*32 + ah;
    _Float16* Bw = Bs + tid*32;
    const int aoff = (wr*64  + (lane & 15))*32 + (lane >> 4)*8;
    const int boff = (wc*128 + (lane & 15))*32 + (lane >> 4)*8;

    for (int kt = 0; kt < 16; ++kt) {
        const int ko = kt*32;
        float4 a0 = *(const float4*)(Ag + ko);
        float4 a1 = *(const float4*)(Ag + ko + 4);
        float4 a2 = *(const float4*)(Ag + ko + 8);
        float4 a3 = *(const float4*)(Ag + ko + 12);
        float4 b0 = *(const float4*)(Bg + ko);
        float4 b1 = *(const float4*)(Bg + ko + 4);
        float4 b2 = *(const float4*)(Bg + ko + 8);
        float4 b3 = *(const float4*)(Bg + ko + 12);
        float4 b4 = *(const float4*)(Bg + ko + 16);
        float4 b5 = *(const float4*)(Bg + ko + 20);
        float4 b6 = *(const float4*)(Bg + ko + 24);
        float4 b7 = *(const float4*)(Bg + ko + 28);
        __syncthreads();
        *(half8_t*)(Aw)      = cvt8(a0, a1);
        *(half8_t*)(Aw + 8)  = cvt8(a2, a3);
        *(half8_t*)(Bw)      = cvt8(b0, b1);
        *(half8_t*)(Bw + 8)  = cvt8(b2, b3);
        *(half8_t*)(Bw + 16) = cvt8(b4, b5);
        *(half8_t*)(Bw + 24) = cvt8(b6, b7);
        __syncthreads();
        half8_t af[4], bf[8];
#pragma unroll
        for (int f = 0; f < 4; ++f) af[f] = *(const half8_t*)(As + aoff + f*512);
#pragma unroll
        for (int f = 0; f < 8; ++f) bf[f] = *(const half8_t*)(Bs + boff + f*512);
#pragma unroll
        for (int i = 0; i < 4; ++i)
#pragma unroll
            for (int j = 0; j < 8; ++j)
                acc[i][j] = __builtin_amdgcn_mfma_f32_16x16x32_f16(af[i], bf[j], acc[i][j], 0, 0, 0);
    }
#pragma unroll
    for (int i = 0; i < 4; ++i) {
#pragma unroll
        for (int j = 0; j < 8; ++j) {
            int col = n0 + wc*128 + j*16 + (lane & 15);
            float bv = bias[col];
            int dir = col >= 768;
            size_t gib = (size_t)dir * 25165824ull + (size_t)(col - dir*768);
#pragma unroll
            for (int q = 0; q < 4; ++q) {
                int row = m0 + wr*64 + i*16 + (lane >> 4)*4 + q;
                gi[gib + (size_t)row*768] = (_Float16)(acc[i][j][q] + bv);
            }
        }
    }
}

// ---------------- recurrent kernel ----------------
// R16: R15's 3-way W plan (REG 21 / LDS 18 = 144KB / L2-stream 9 groups) rebuilt
// on PROVEN container idioms only: half8_t vectors + pair-extraction (R9/k_gemm),
// no u32 ext-vectors (the R8/R15 failure-correlated idiom). Body = R14-verified.
#define FDOT2v(wp_, h_, acc_) __builtin_amdgcn_fdot2((wp_), (h_), (acc_), false)
#define LBAR()  do { asm volatile("s_waitcnt lgkmcnt(0)" ::: "memory"); \
                     __builtin_amdgcn_s_barrier(); } while (0)

// one pair-quad: gate fragments R(gate0) Z(gate1) N(gate2), h octet H
#define PQH(Hv, Rv, Zv, Nv) do { \
    half8_t H_ = (Hv), R_ = (Rv), Z_ = (Zv), N_ = (Nv); \
    half2_t h0_ = {H_[0], H_[1]}, h1_ = {H_[2], H_[3]}; \
    half2_t h2_ = {H_[4], H_[5]}, h3_ = {H_[6], H_[7]}; \
    half2_t t0_, t1_, t2_, t3_; \
    t0_ = (half2_t){R_[0], R_[1]};  t1_ = (half2_t){R_[2], R_[3]}; \
    t2_ = (half2_t){R_[4], R_[5]};  t3_ = (half2_t){R_[6], R_[7]}; \
    a0 = FDOT2v(t0_, h0_, a0);  b0 = FDOT2v(t1_, h1_, b0); \
    a0 = FDOT2v(t2_, h2_, a0);  b0 = FDOT2v(t3_, h3_, b0); \
    t0_ = (half2_t){Z_[0], Z_[1]};  t1_ = (half2_t){Z_[2], Z_[3]}; \
    t2_ = (half2_t){Z_[4], Z_[5]};  t3_ = (half2_t){Z_[6], Z_[7]}; \
    a1 = FDOT2v(t0_, h0_, a1);  b1 = FDOT2v(t1_, h1_, b1); \
    a1 = FDOT2v(t2_, h2_, a1);  b1 = FDOT2v(t3_, h3_, b1); \
    t0_ = (half2_t){N_[0], N_[1]};  t1_ = (half2_t){N_[2], N_[3]}; \
    t2_ = (half2_t){N_[4], N_[5]};  t3_ = (half2_t){N_[6], N_[7]}; \
    a2 = FDOT2v(t0_, h0_, a2);  b2 = FDOT2v(t1_, h1_, b2); \
    a2 = FDOT2v(t2_, h2_, a2);  b2 = FDOT2v(t3_, h3_, b2); } while (0)

#define HOCT(pq) (*(const half8_t*)(hrd + ((pq) << 3)))

__global__ __launch_bounds__(512) void k_rnn(const _Float16* __restrict__ wp,
                                             const _Float16* __restrict__ gi,
                                             const float* __restrict__ mask,
                                             const float* __restrict__ bhh1,
                                             const float* __restrict__ bhh2,
                                             float* __restrict__ outp) {
    __shared__ __align__(16) half8_t wlds[18*512];   // 144 KB W slice
    __shared__ __align__(16) _Float16 hs16[256];
    __shared__ float part[768];
    const int tid = threadIdx.x;
    const int bid = blockIdx.x;
    const int dir = bid >> 6, b = bid & 63;
    const int c  = tid & 255;
    const int kh = tid >> 8;

    const half8_t* wme = (const half8_t*)wp + (size_t)(dir*48)*512 + tid;
    half8_t wreg[21];                                // REG slice (G 0..20), coalesced
#pragma unroll
    for (int G = 0; G < 21; ++G) wreg[G] = wme[G*512];
#pragma unroll
    for (int G = 21; G < 39; ++G)                    // LDS slice (G 21..38)
        wlds[(G-21)*512 + tid] = wme[G*512];
    const half8_t* wstr = wme + 39*512;              // stream slice (G 39..47)

    const float bhn = (dir ? bhh2 : bhh1)[512 + c];
    if (tid < 256) hs16[tid] = (_Float16)0.f;
    float h_c = 0.f;
    __syncthreads();

    const _Float16* gb = gi + (size_t)dir * 25165824ull + c;
    const _Float16* hrd = hs16 + (kh << 7);

#pragma unroll 1
    for (int s = 0; s < 512; ++s) {
        const int t = dir ? (511 - s) : s;
        const float mv = mask[t*64 + b];             // WG-uniform
        if (mv != 0.f) {
            float g0 = 0.f, g1 = 0.f, g2 = 0.f;
            if (tid < 256) {
                const _Float16* gp = gb + (size_t)(t*64 + b)*768;
                g0 = (float)gp[0];
                g1 = (float)gp[256];
                g2 = (float)gp[512];
            }
            float a0 = 0.f, a1 = 0.f, a2 = 0.f;
            float b0 = 0.f, b1 = 0.f, b2 = 0.f;
            // stream chunk 1 (gate2 pairs 28..39, consumed pq 7..9)
            half8_t s0 = wstr[0*512], s1 = wstr[1*512], s2 = wstr[2*512];
            // pq 0..4: gate0 REG, gate1 REG, gate2 LDS(L=11+pq)
#pragma unroll
            for (int pq = 0; pq < 5; ++pq)
                PQH(HOCT(pq), wreg[pq], wreg[16+pq], wlds[(11+pq)*512 + tid]);
            // stream chunk 2 (consumed pq 10..12)
            half8_t s3 = wstr[3*512], s4 = wstr[4*512], s5 = wstr[5*512];
            // pq 5..6: gate0 REG, gate1 LDS(L=pq-5), gate2 LDS(L=11+pq)
#pragma unroll
            for (int pq = 5; pq < 7; ++pq)
                PQH(HOCT(pq), wreg[pq], wlds[(pq-5)*512 + tid], wlds[(11+pq)*512 + tid]);
            // pq 7..9: gate2 from stream chunk 1
            PQH(HOCT(7), wreg[7], wlds[2*512 + tid], s0);
            PQH(HOCT(8), wreg[8], wlds[3*512 + tid], s1);
            PQH(HOCT(9), wreg[9], wlds[4*512 + tid], s2);
            // stream chunk 3 (consumed pq 13..15)
            half8_t s6 = wstr[6*512], s7 = wstr[7*512], s8 = wstr[8*512];
            PQH(HOCT(10), wreg[10], wlds[5*512 + tid], s3);
            PQH(HOCT(11), wreg[11], wlds[6*512 + tid], s4);
            PQH(HOCT(12), wreg[12], wlds[7*512 + tid], s5);
            PQH(HOCT(13), wreg[13], wlds[8*512 + tid], s6);
            PQH(HOCT(14), wreg[14], wlds[9*512 + tid], s7);
            PQH(HOCT(15), wreg[15], wlds[10*512 + tid], s8);
            a0 += b0; a1 += b1; a2 += b2;
            if (tid >= 256) { part[c] = a0; part[256 + c] = a1; part[512 + c] = a2; }
            LBAR();
            if (tid < 256) {
                float ghr = a0 + part[c];
                float ghz = a1 + part[256 + c];
                float ghn = a2 + part[512 + c];
                float r = 1.f / (1.f + __expf(-(g0 + ghr)));
                float z = 1.f / (1.f + __expf(-(g1 + ghz)));
                float tt = g2 + r * (ghn + bhn);
                float ea = __expf(-2.f * fabsf(tt));
                float nt = (1.f - ea) / (1.f + ea);
                nt = (tt < 0.f) ? -nt : nt;
                float ht = (1.f - z) * nt + z * h_c;
                h_c = ht;
                hs16[c] = (_Float16)ht;
                outp[(size_t)(t*64 + b)*512 + dir*256 + c] = ht;
            }
            LBAR();
        } else {
            if (tid < 256)
                outp[(size_t)(t*64 + b)*512 + dir*256 + c] = 0.f;
        }
    }
    if (tid < 256) {
        outp[16777216u + dir*16384 + b*256 + c] = h_c;
    }
}

// ---------------- launch ----------------
extern "C" void kernel_launch(void* const* d_in, const int* in_sizes, int n_in,
                              void* d_out, int out_size, void* d_ws, size_t ws_size,
                              hipStream_t stream) {
    const float* x    = (const float*)d_in[0];
    const float* mask = (const float*)d_in[1];
    const float* Wih1 = (const float*)d_in[2];
    const float* Whh1 = (const float*)d_in[3];
    const float* bih1 = (const float*)d_in[4];
    const float* bhh1 = (const float*)d_in[5];
    const float* Wih2 = (const float*)d_in[6];
    const float* Whh2 = (const float*)d_in[7];
    const float* bih2 = (const float*)d_in[8];
    const float* bhh2 = (const float*)d_in[9];
    char* ws = (char*)d_ws;
    float* biascat = (float*)(ws + OFF_BIAS);
    _Float16* wp   = (_Float16*)(ws + OFF_WP);
    _Float16* gi   = (_Float16*)(ws + OFF_GI);
    float* outp = (float*)d_out;

    hipLaunchKernelGGL(k_prep, dim3(198), dim3(256), 0, stream,
                       Whh1, Whh2, bih1, bih2, bhh1, bhh2, wp, biascat);
    hipLaunchKernelGGL(k_gemm, dim3(256, 6), dim3(256), 0, stream, x, Wih1, Wih2, biascat, gi);
    hipLaunchKernelGGL(k_rnn, dim3(128), dim3(512), 0, stream,
                       wp, gi, mask, bhh1, bhh2, outp);
}